// Round 7
// baseline (1478.028 us; speedup 1.0000x reference)
//
#include <hip/hip_runtime.h>
#include <hip/hip_bf16.h>

typedef __attribute__((ext_vector_type(4))) float f32x4;
typedef __attribute__((ext_vector_type(4))) int   i32x4;
typedef __attribute__((ext_vector_type(8))) short s16x8;
typedef unsigned short ushort_t;

#define MDIM 8192
#define KDIM 4096
#define NDIM 16384
#define NKT  (KDIM / 32)        // 128 K-tiles of BK=32

static __device__ __forceinline__ short f2bf(float f) {
    __bf16 h = (__bf16)f;
    return __builtin_bit_cast(short, h);
}

static __device__ __forceinline__ void gload_lds16(const void* g, void* l) {
    __builtin_amdgcn_global_load_lds(
        (const __attribute__((address_space(1))) unsigned int*)g,
        (__attribute__((address_space(3))) unsigned int*)l,
        16, 0, 0);
}

// ---------------- convert kernels (memory-bound, vectorized) ----------------

__global__ __launch_bounds__(256)
void cvt_f32_bf16(const float* __restrict__ in, ushort_t* __restrict__ out, int n8) {
    for (int i = blockIdx.x * blockDim.x + threadIdx.x; i < n8;
         i += gridDim.x * blockDim.x) {
        f32x4 a = ((const f32x4*)in)[i * 2];
        f32x4 b = ((const f32x4*)in)[i * 2 + 1];
        s16x8 o;
        #pragma unroll
        for (int q = 0; q < 4; ++q) o[q] = f2bf(a[q]);
        #pragma unroll
        for (int q = 0; q < 4; ++q) o[4 + q] = f2bf(b[q]);
        ((s16x8*)out)[i] = o;
    }
}

__global__ __launch_bounds__(256)
void cvt_i32_bf16(const int* __restrict__ in, ushort_t* __restrict__ out, int n8) {
    for (int i = blockIdx.x * blockDim.x + threadIdx.x; i < n8;
         i += gridDim.x * blockDim.x) {
        i32x4 a = ((const i32x4*)in)[i * 2];
        i32x4 b = ((const i32x4*)in)[i * 2 + 1];
        s16x8 o;
        #pragma unroll
        for (int q = 0; q < 4; ++q) o[q] = f2bf((float)a[q]);   // |v|<=127: exact
        #pragma unroll
        for (int q = 0; q < 4; ++q) o[4 + q] = f2bf((float)b[q]);
        ((s16x8*)out)[i] = o;
    }
}

// ---------------- 256x256 bf16 GEMM, ring-4 LDS, cross-tile reg dbuf -------
// Identical hazard structure to R6 (verified correct):
//   buf (it+1)&3 : 16 ds_reads into R_next        (tile it+1)
//   buf (it+3)&3 : overwritten by staging tile it+3 (WAR-safe via barrier)
//   trailing {vmcnt(4); s_barrier; sched_barrier(0)} per K-tile, never 0.
// R7 change: intra-tile ISSUE ORDER only. 8 quads of {2 ds_reads -> 4 MFMA}
// with SB0 fences, gloads spread 1/quad in quads 4-7 -> LDS pipe and matrix
// pipe stay simultaneously fed instead of flood-then-drain (R6: serial).
// Loop unrolled x4 so ring offsets are compile-time (imm-offset folding).

#define BAR()   __builtin_amdgcn_s_barrier()
#define SB0()   __builtin_amdgcn_sched_barrier(0)
#define PRIO(N) __builtin_amdgcn_s_setprio(N)

#define MFMA4(CA, CB, M)                                                       \
    PRIO(1);                                                                   \
    acc[M][0] = __builtin_amdgcn_mfma_f32_16x16x32_bf16(CA[M], CB[0], acc[M][0], 0, 0, 0); \
    acc[M][1] = __builtin_amdgcn_mfma_f32_16x16x32_bf16(CA[M], CB[1], acc[M][1], 0, 0, 0); \
    acc[M][2] = __builtin_amdgcn_mfma_f32_16x16x32_bf16(CA[M], CB[2], acc[M][2], 0, 0, 0); \
    acc[M][3] = __builtin_amdgcn_mfma_f32_16x16x32_bf16(CA[M], CB[3], acc[M][3], 0, 0, 0); \
    PRIO(0); SB0();

// one K-tile: MFMAs on CUR regs, ds_reads into NXT regs, stage tile IT+3.
// RB/WB are compile-time byte offsets of the read/write ring buffers.
#define KTILE(CA, CB, NA, NB, IT, RB, WB)                                      \
  {                                                                            \
    const char* rbuf = ldsc + (RB);                                            \
    char*       wbuf = ldsc + (WB);                                            \
    const size_t ko  = (size_t)(((IT) + 3) & (NKT - 1)) * 32;                  \
    /* q0 */ NB[0] = *(const s16x8*)(rbuf + boff[0]);                          \
             NB[1] = *(const s16x8*)(rbuf + boff[1]);                          \
    MFMA4(CA, CB, 0)                                                           \
    /* q1 */ NB[2] = *(const s16x8*)(rbuf + boff[2]);                          \
             NB[3] = *(const s16x8*)(rbuf + boff[3]);                          \
    MFMA4(CA, CB, 1)                                                           \
    /* q2 */ NA[0] = *(const s16x8*)(rbuf + aoff[0]);                          \
             NA[1] = *(const s16x8*)(rbuf + aoff[1]);                          \
    MFMA4(CA, CB, 2)                                                           \
    /* q3 */ NA[2] = *(const s16x8*)(rbuf + aoff[2]);                          \
             NA[3] = *(const s16x8*)(rbuf + aoff[3]);                          \
    MFMA4(CA, CB, 3)                                                           \
    /* q4 */ NA[4] = *(const s16x8*)(rbuf + aoff[4]);                          \
             NA[5] = *(const s16x8*)(rbuf + aoff[5]);                          \
             gload_lds16(pA0 + ko, wbuf + ldsw);                               \
    MFMA4(CA, CB, 4)                                                           \
    /* q5 */ NA[6] = *(const s16x8*)(rbuf + aoff[6]);                          \
             NA[7] = *(const s16x8*)(rbuf + aoff[7]);                          \
             gload_lds16(pA1 + ko, wbuf + 8192 + ldsw);                        \
    MFMA4(CA, CB, 5)                                                           \
    /* q6 */ gload_lds16(pB0 + ko, wbuf + 16384 + ldsw);                       \
    MFMA4(CA, CB, 6)                                                           \
    /* q7 */ gload_lds16(pB1 + ko, wbuf + 24576 + ldsw);                       \
    MFMA4(CA, CB, 7)                                                           \
    asm volatile("s_waitcnt vmcnt(4)" ::: "memory");                           \
    BAR();                                                                     \
    SB0();                                                                     \
  }

__global__ __launch_bounds__(512, 2)
void sl_gemm_256i(const ushort_t* __restrict__ A, const ushort_t* __restrict__ Bw,
                  const float* __restrict__ scale_p, const float* __restrict__ bias,
                  float* __restrict__ Out)
{
    __shared__ char ldsbuf[131072];   // 4 bufs x (A 16 KB + B 16 KB)
    char* ldsc = ldsbuf;

    const int t    = threadIdx.x;
    const int lane = t & 63;
    const int wave = t >> 6;        // 0..7
    const int wr   = wave >> 2;     // 0..1 : 128 output rows each
    const int wc   = wave & 3;      // 0..3 : 64  output cols each

    // ---- tile mapping: XCD chunks of 256, then 16-tn panels, tm fastest
    int bid = blockIdx.x;                       // 2048 blocks (32 tm x 64 tn)
    int swz = (bid & 7) * 256 + (bid >> 3);
    int panel = swz >> 9, inp = swz & 511;
    int tn = (panel << 4) + (inp >> 5);
    int tm = inp & 31;
    const int m0 = tm << 8;
    const int n0 = tn << 8;

    // ---- staging geometry (verbatim R4/R6): thread covers row
    //      (wave*16 + lane>>2) of a 128-row chunk, physical slot lane&3
    const int srow  = wave * 16 + (lane >> 2);            // 0..127
    const int sslot = lane & 3;
    const int sA    = sslot ^ ((srow >> 1) & 3);          // logical slot
    const ushort_t* pA0 = A  + (size_t)(m0 + srow) * KDIM + sA * 8;
    const ushort_t* pA1 = pA0 + (size_t)128 * KDIM;
    const ushort_t* pB0 = Bw + (size_t)(n0 + srow) * KDIM + sA * 8;
    const ushort_t* pB1 = pB0 + (size_t)128 * KDIM;
    const int ldsw = wave * 1024;                          // wave-uniform dest

    // ---- fragment read offsets (byte, buf-relative; verbatim R4/R6)
    const int fr = lane & 15;
    const int fs = lane >> 4;                              // 0..3
    int aoff[8], boff[4];
    #pragma unroll
    for (int i = 0; i < 8; ++i) {
        int ra = wr * 128 + i * 16 + fr;
        aoff[i] = ra * 64 + ((fs ^ ((ra >> 1) & 3)) * 16);
    }
    #pragma unroll
    for (int j = 0; j < 4; ++j) {
        int rb = wc * 64 + j * 16 + fr;
        boff[j] = 16384 + rb * 64 + ((fs ^ ((rb >> 1) & 3)) * 16);
    }

    f32x4 acc[8][4];
    #pragma unroll
    for (int i = 0; i < 8; ++i)
        #pragma unroll
        for (int j = 0; j < 4; ++j)
            acc[i][j] = (f32x4){0.f, 0.f, 0.f, 0.f};

    // ---- prologue: stage tiles 0,1,2 -> bufs 0,1,2
    #pragma unroll
    for (int kt = 0; kt < 3; ++kt) {
        const size_t ko = (size_t)kt * 32;
        char* b = ldsc + kt * 32768;
        gload_lds16(pA0 + ko, b + ldsw);
        gload_lds16(pA1 + ko, b + 8192  + ldsw);
        gload_lds16(pB0 + ko, b + 16384 + ldsw);
        gload_lds16(pB1 + ko, b + 24576 + ldsw);
    }
    asm volatile("s_waitcnt vmcnt(4)" ::: "memory");   // tiles 0,1 landed
    BAR();
    SB0();

    // R_cur <- tile 0 fragments (buf 0)
    s16x8 FA[8], FB[4], GA[8], GB[4];
    #pragma unroll
    for (int i = 0; i < 8; ++i) FA[i] = *(const s16x8*)(ldsc + aoff[i]);
    #pragma unroll
    for (int j = 0; j < 4; ++j) FB[j] = *(const s16x8*)(ldsc + boff[j]);

    // ring positions mod 4 are compile-time per unrolled slot:
    //   slot p: read buf (p+1)&3, write buf (p+3)&3
    for (int it = 0; it < NKT; it += 4) {
        KTILE(FA, FB, GA, GB, it + 0, 1 * 32768, 3 * 32768);
        KTILE(GA, GB, FA, FB, it + 1, 2 * 32768, 0 * 32768);
        KTILE(FA, FB, GA, GB, it + 2, 3 * 32768, 1 * 32768);
        KTILE(GA, GB, FA, FB, it + 3, 0 * 32768, 2 * 32768);
    }

    // ---- epilogue: D col = lane&15, row = fs*4 + q; scale + bias
    const float scale = scale_p[0];
    #pragma unroll
    for (int j = 0; j < 4; ++j) {
        const int c   = n0 + wc * 64 + j * 16 + fr;
        const float bj = bias[c];
        #pragma unroll
        for (int i = 0; i < 8; ++i) {
            const int r0 = m0 + wr * 128 + i * 16 + fs * 4;
            float* op = Out + (size_t)r0 * NDIM + c;
            #pragma unroll
            for (int q = 0; q < 4; ++q)
                op[(size_t)q * NDIM] = acc[i][j][q] * scale + bj;
        }
    }
}

// ---------------- fallback (fp32 direct, no workspace) ----------------

__global__ __launch_bounds__(256, 2)
void sl_gemm_fb(const float* __restrict__ X, const int* __restrict__ Wq,
                const float* __restrict__ scale_p, const float* __restrict__ bias,
                float* __restrict__ Out)
{
    __shared__ s16x8 As[128 * 4];
    __shared__ s16x8 Bs[128 * 4];

    const int t    = threadIdx.x;
    const int lane = t & 63;
    const int wave = t >> 6;
    const int wr   = wave >> 1;
    const int wc   = wave & 1;

    int bid = blockIdx.x;
    int swz = (bid & 7) * 1024 + (bid >> 3);
    int panel   = swz >> 10;
    int inpanel = swz & 1023;
    int tn = (panel << 4) + (inpanel >> 6);
    int tm = inpanel & 63;
    const int m0 = tm << 7;
    const int n0 = tn << 7;

    const int srow  = t >> 1;
    const int shalf = t & 1;
    const float* Xp = X  + (size_t)(m0 + srow) * KDIM + shalf * 16;
    const int*   Wp = Wq + (size_t)(n0 + srow) * KDIM + shalf * 16;

    f32x4 acc[4][4];
    #pragma unroll
    for (int i = 0; i < 4; ++i)
        #pragma unroll
        for (int j = 0; j < 4; ++j)
            acc[i][j] = (f32x4){0.f, 0.f, 0.f, 0.f};

    const int fr = lane & 15;
    const int fs = lane >> 4;

    f32x4 ar[4];
    i32x4 br[4];
    #pragma unroll
    for (int p = 0; p < 4; ++p) {
        ar[p] = *(const f32x4*)(Xp + p * 4);
        br[p] = *(const i32x4*)(Wp + p * 4);
    }

    const int wbase = srow * 4;
    const int wswz  = (srow >> 1) & 3;
    const int ws0   = (shalf * 2)     ^ wswz;
    const int ws1   = (shalf * 2 + 1) ^ wswz;

    for (int kt = 0; kt < KDIM / 32; ++kt) {
        __syncthreads();
        {
            s16x8 v0, v1;
            #pragma unroll
            for (int q = 0; q < 8; ++q) v0[q] = f2bf(ar[q >> 2][q & 3]);
            #pragma unroll
            for (int q = 0; q < 8; ++q) v1[q] = f2bf(ar[2 + (q >> 2)][q & 3]);
            As[wbase + ws0] = v0;
            As[wbase + ws1] = v1;
            s16x8 u0, u1;
            #pragma unroll
            for (int q = 0; q < 8; ++q) u0[q] = f2bf((float)br[q >> 2][q & 3]);
            #pragma unroll
            for (int q = 0; q < 8; ++q) u1[q] = f2bf((float)br[2 + (q >> 2)][q & 3]);
            Bs[wbase + ws0] = u0;
            Bs[wbase + ws1] = u1;
        }
        __syncthreads();

        if (kt + 1 < KDIM / 32) {
            const float* Xn = Xp + (size_t)(kt + 1) * 32;
            const int*   Wn = Wp + (size_t)(kt + 1) * 32;
            #pragma unroll
            for (int p = 0; p < 4; ++p) {
                ar[p] = *(const f32x4*)(Xn + p * 4);
                br[p] = *(const i32x4*)(Wn + p * 4);
            }
        }

        s16x8 af[4], bq[4];
        #pragma unroll
        for (int i = 0; i < 4; ++i) {
            int row = wr * 64 + i * 16 + fr;
            af[i] = As[row * 4 + (fs ^ ((row >> 1) & 3))];
        }
        #pragma unroll
        for (int j = 0; j < 4; ++j) {
            int col = wc * 64 + j * 16 + fr;
            bq[j] = Bs[col * 4 + (fs ^ ((col >> 1) & 3))];
        }
        #pragma unroll
        for (int i = 0; i < 4; ++i)
            #pragma unroll
            for (int j = 0; j < 4; ++j)
                acc[i][j] = __builtin_amdgcn_mfma_f32_16x16x32_bf16(
                    af[i], bq[j], acc[i][j], 0, 0, 0);
    }

    const float scale = scale_p[0];
    #pragma unroll
    for (int j = 0; j < 4; ++j) {
        const int c  = n0 + wc * 64 + j * 16 + fr;
        const float bj = bias[c];
        #pragma unroll
        for (int i = 0; i < 4; ++i) {
            const int r0 = m0 + wr * 64 + i * 16 + fs * 4;
            float* op = Out + (size_t)r0 * NDIM + c;
            #pragma unroll
            for (int q = 0; q < 4; ++q)
                op[(size_t)q * NDIM] = acc[i][j][q] * scale + bj;
        }
    }
}

extern "C" void kernel_launch(void* const* d_in, const int* in_sizes, int n_in,
                              void* d_out, int out_size, void* d_ws, size_t ws_size,
                              hipStream_t stream) {
    const float* X     = (const float*)d_in[0];
    const int*   Wq    = (const int*)d_in[1];   // int8 widened to int32 by harness
    const float* scale = (const float*)d_in[2];
    const float* bias  = (const float*)d_in[3];
    float*       Out   = (float*)d_out;

    const size_t xBytes = (size_t)MDIM * KDIM * 2;          // 67 MB
    const size_t wBytes = (size_t)NDIM * KDIM * 2;          // 134 MB
    if (ws_size >= xBytes + wBytes) {
        ushort_t* Xbf = (ushort_t*)d_ws;
        ushort_t* Wbf = (ushort_t*)((char*)d_ws + xBytes);
        hipLaunchKernelGGL(cvt_f32_bf16, dim3(2048), dim3(256), 0, stream,
                           X, Xbf, MDIM * KDIM / 8);
        hipLaunchKernelGGL(cvt_i32_bf16, dim3(2048), dim3(256), 0, stream,
                           Wq, Wbf, NDIM * KDIM / 8);
        hipLaunchKernelGGL(sl_gemm_256i, dim3(2048), dim3(512), 0, stream,
                           Xbf, Wbf, scale, bias, Out);
    } else {
        hipLaunchKernelGGL(sl_gemm_fb, dim3(8192), dim3(256), 0, stream,
                           X, Wq, scale, bias, Out);
    }
}

// Round 8
// 1449.292 us; speedup vs baseline: 1.0198x; 1.0198x over previous
//
#include <hip/hip_runtime.h>
#include <hip/hip_bf16.h>

typedef __attribute__((ext_vector_type(4))) float f32x4;
typedef __attribute__((ext_vector_type(4))) int   i32x4;
typedef __attribute__((ext_vector_type(8))) short s16x8;
typedef unsigned short ushort_t;

#define MDIM 8192
#define KDIM 4096
#define NDIM 16384
#define NKT  (KDIM / 32)        // 128 K-tiles of BK=32

static __device__ __forceinline__ short f2bf(float f) {
    __bf16 h = (__bf16)f;
    return __builtin_bit_cast(short, h);
}

static __device__ __forceinline__ void gload_lds16(const void* g, void* l) {
    __builtin_amdgcn_global_load_lds(
        (const __attribute__((address_space(1))) unsigned int*)g,
        (__attribute__((address_space(3))) unsigned int*)l,
        16, 0, 0);
}

// ---------------- convert kernels (memory-bound, vectorized) ----------------

__global__ __launch_bounds__(256)
void cvt_f32_bf16(const float* __restrict__ in, ushort_t* __restrict__ out, int n8) {
    for (int i = blockIdx.x * blockDim.x + threadIdx.x; i < n8;
         i += gridDim.x * blockDim.x) {
        f32x4 a = ((const f32x4*)in)[i * 2];
        f32x4 b = ((const f32x4*)in)[i * 2 + 1];
        s16x8 o;
        #pragma unroll
        for (int q = 0; q < 4; ++q) o[q] = f2bf(a[q]);
        #pragma unroll
        for (int q = 0; q < 4; ++q) o[4 + q] = f2bf(b[q]);
        ((s16x8*)out)[i] = o;
    }
}

__global__ __launch_bounds__(256)
void cvt_i32_bf16(const int* __restrict__ in, ushort_t* __restrict__ out, int n8) {
    for (int i = blockIdx.x * blockDim.x + threadIdx.x; i < n8;
         i += gridDim.x * blockDim.x) {
        i32x4 a = ((const i32x4*)in)[i * 2];
        i32x4 b = ((const i32x4*)in)[i * 2 + 1];
        s16x8 o;
        #pragma unroll
        for (int q = 0; q < 4; ++q) o[q] = f2bf((float)a[q]);   // |v|<=127: exact
        #pragma unroll
        for (int q = 0; q < 4; ++q) o[4 + q] = f2bf((float)b[q]);
        ((s16x8*)out)[i] = o;
    }
}

// ---------------- 256x256 bf16 GEMM, ring-4 LDS, MFMA-first issue ----------
// Hazard structure identical to R6 (verified correct):
//   buf (it+1)&3 : 16 ds_reads into R_next        (tile it+1)
//   buf (it+3)&3 : overwritten by staging tile it+3 (WAR-safe: its last
//     readers drained two barriers ago; barrier collectiveness publishes)
//   trailing {vmcnt(4); s_barrier; sched_barrier(0)} per K-tile, never 0.
// R8 change (issue ORDER only, cannot affect hazard proofs):
//   [32 MFMA on CUR regs] [SB0] [16 ds_reads -> NXT regs] [4 gloads]
//   [vmcnt(4)] [BAR] [SB0]
// MFMAs have zero dependency on this tile's reads -> they issue immediately
// after the barrier and fill the matrix pipe (~1242 cyc of work/SIMD);
// ds_reads + staging issue under that shadow instead of blocking MFMA issue
// at tile start (R6's flood-then-drain). Ring offsets compile-time via x4
// unroll (R7's proven VALU reduction).

#define BAR()   __builtin_amdgcn_s_barrier()
#define SB0()   __builtin_amdgcn_sched_barrier(0)
#define PRIO(N) __builtin_amdgcn_s_setprio(N)

// one K-tile: MFMAs on CUR regs first, then ds_reads into NXT regs,
// then stage tile IT+3. RB/WB are compile-time ring byte offsets.
#define KTILE(CA, CB, NA, NB, IT, RB, WB)                                      \
  {                                                                            \
    const char* rbuf = ldsc + (RB);                                            \
    char*       wbuf = ldsc + (WB);                                            \
    const size_t ko  = (size_t)(((IT) + 3) & (NKT - 1)) * 32;                  \
    PRIO(1);                                                                   \
    _Pragma("unroll")                                                          \
    for (int m = 0; m < 8; ++m)                                                \
      _Pragma("unroll")                                                        \
      for (int nn = 0; nn < 4; ++nn)                                           \
        acc[m][nn] = __builtin_amdgcn_mfma_f32_16x16x32_bf16(                  \
            CA[m], CB[nn], acc[m][nn], 0, 0, 0);                               \
    PRIO(0);                                                                   \
    SB0();  /* matrix pipe fed first; reads issue under its shadow */          \
    _Pragma("unroll")                                                          \
    for (int j = 0; j < 4; ++j) NB[j] = *(const s16x8*)(rbuf + boff[j]);       \
    _Pragma("unroll")                                                          \
    for (int i = 0; i < 8; ++i) NA[i] = *(const s16x8*)(rbuf + aoff[i]);       \
    gload_lds16(pA0 + ko, wbuf + ldsw);                                        \
    gload_lds16(pA1 + ko, wbuf + 8192  + ldsw);                                \
    gload_lds16(pB0 + ko, wbuf + 16384 + ldsw);                                \
    gload_lds16(pB1 + ko, wbuf + 24576 + ldsw);                                \
    asm volatile("s_waitcnt vmcnt(4)" ::: "memory");                           \
    BAR();                                                                     \
    SB0();                                                                     \
  }

__global__ __launch_bounds__(512, 2)
void sl_gemm_256m(const ushort_t* __restrict__ A, const ushort_t* __restrict__ Bw,
                  const float* __restrict__ scale_p, const float* __restrict__ bias,
                  float* __restrict__ Out)
{
    __shared__ char ldsbuf[131072];   // 4 bufs x (A 16 KB + B 16 KB)
    char* ldsc = ldsbuf;

    const int t    = threadIdx.x;
    const int lane = t & 63;
    const int wave = t >> 6;        // 0..7
    const int wr   = wave >> 2;     // 0..1 : 128 output rows each
    const int wc   = wave & 3;      // 0..3 : 64  output cols each

    // ---- tile mapping: XCD chunks of 256, then 16-tn panels, tm fastest
    int bid = blockIdx.x;                       // 2048 blocks (32 tm x 64 tn)
    int swz = (bid & 7) * 256 + (bid >> 3);
    int panel = swz >> 9, inp = swz & 511;
    int tn = (panel << 4) + (inp >> 5);
    int tm = inp & 31;
    const int m0 = tm << 8;
    const int n0 = tn << 8;

    // ---- staging geometry (verbatim R4/R6): thread covers row
    //      (wave*16 + lane>>2) of a 128-row chunk, physical slot lane&3
    const int srow  = wave * 16 + (lane >> 2);            // 0..127
    const int sslot = lane & 3;
    const int sA    = sslot ^ ((srow >> 1) & 3);          // logical slot
    const ushort_t* pA0 = A  + (size_t)(m0 + srow) * KDIM + sA * 8;
    const ushort_t* pA1 = pA0 + (size_t)128 * KDIM;
    const ushort_t* pB0 = Bw + (size_t)(n0 + srow) * KDIM + sA * 8;
    const ushort_t* pB1 = pB0 + (size_t)128 * KDIM;
    const int ldsw = wave * 1024;                          // wave-uniform dest

    // ---- fragment read offsets (byte, buf-relative; verbatim R4/R6)
    const int fr = lane & 15;
    const int fs = lane >> 4;                              // 0..3
    int aoff[8], boff[4];
    #pragma unroll
    for (int i = 0; i < 8; ++i) {
        int ra = wr * 128 + i * 16 + fr;
        aoff[i] = ra * 64 + ((fs ^ ((ra >> 1) & 3)) * 16);
    }
    #pragma unroll
    for (int j = 0; j < 4; ++j) {
        int rb = wc * 64 + j * 16 + fr;
        boff[j] = 16384 + rb * 64 + ((fs ^ ((rb >> 1) & 3)) * 16);
    }

    f32x4 acc[8][4];
    #pragma unroll
    for (int i = 0; i < 8; ++i)
        #pragma unroll
        for (int j = 0; j < 4; ++j)
            acc[i][j] = (f32x4){0.f, 0.f, 0.f, 0.f};

    // ---- prologue: stage tiles 0,1,2 -> bufs 0,1,2
    #pragma unroll
    for (int kt = 0; kt < 3; ++kt) {
        const size_t ko = (size_t)kt * 32;
        char* b = ldsc + kt * 32768;
        gload_lds16(pA0 + ko, b + ldsw);
        gload_lds16(pA1 + ko, b + 8192  + ldsw);
        gload_lds16(pB0 + ko, b + 16384 + ldsw);
        gload_lds16(pB1 + ko, b + 24576 + ldsw);
    }
    asm volatile("s_waitcnt vmcnt(4)" ::: "memory");   // tiles 0,1 landed
    BAR();
    SB0();

    // R_cur <- tile 0 fragments (buf 0)
    s16x8 FA[8], FB[4], GA[8], GB[4];
    #pragma unroll
    for (int i = 0; i < 8; ++i) FA[i] = *(const s16x8*)(ldsc + aoff[i]);
    #pragma unroll
    for (int j = 0; j < 4; ++j) FB[j] = *(const s16x8*)(ldsc + boff[j]);

    // ring positions mod 4 are compile-time per unrolled slot:
    //   slot p: read buf (p+1)&3, write buf (p+3)&3
    for (int it = 0; it < NKT; it += 4) {
        KTILE(FA, FB, GA, GB, it + 0, 1 * 32768, 3 * 32768);
        KTILE(GA, GB, FA, FB, it + 1, 2 * 32768, 0 * 32768);
        KTILE(FA, FB, GA, GB, it + 2, 3 * 32768, 1 * 32768);
        KTILE(GA, GB, FA, FB, it + 3, 0 * 32768, 2 * 32768);
    }

    // ---- epilogue: D col = lane&15, row = fs*4 + q; scale + bias
    const float scale = scale_p[0];
    #pragma unroll
    for (int j = 0; j < 4; ++j) {
        const int c   = n0 + wc * 64 + j * 16 + fr;
        const float bj = bias[c];
        #pragma unroll
        for (int i = 0; i < 8; ++i) {
            const int r0 = m0 + wr * 128 + i * 16 + fs * 4;
            float* op = Out + (size_t)r0 * NDIM + c;
            #pragma unroll
            for (int q = 0; q < 4; ++q)
                op[(size_t)q * NDIM] = acc[i][j][q] * scale + bj;
        }
    }
}

// ---------------- fallback (fp32 direct, no workspace) ----------------

__global__ __launch_bounds__(256, 2)
void sl_gemm_fb(const float* __restrict__ X, const int* __restrict__ Wq,
                const float* __restrict__ scale_p, const float* __restrict__ bias,
                float* __restrict__ Out)
{
    __shared__ s16x8 As[128 * 4];
    __shared__ s16x8 Bs[128 * 4];

    const int t    = threadIdx.x;
    const int lane = t & 63;
    const int wave = t >> 6;
    const int wr   = wave >> 1;
    const int wc   = wave & 1;

    int bid = blockIdx.x;
    int swz = (bid & 7) * 1024 + (bid >> 3);
    int panel   = swz >> 10;
    int inpanel = swz & 1023;
    int tn = (panel << 4) + (inpanel >> 6);
    int tm = inpanel & 63;
    const int m0 = tm << 7;
    const int n0 = tn << 7;

    const int srow  = t >> 1;
    const int shalf = t & 1;
    const float* Xp = X  + (size_t)(m0 + srow) * KDIM + shalf * 16;
    const int*   Wp = Wq + (size_t)(n0 + srow) * KDIM + shalf * 16;

    f32x4 acc[4][4];
    #pragma unroll
    for (int i = 0; i < 4; ++i)
        #pragma unroll
        for (int j = 0; j < 4; ++j)
            acc[i][j] = (f32x4){0.f, 0.f, 0.f, 0.f};

    const int fr = lane & 15;
    const int fs = lane >> 4;

    f32x4 ar[4];
    i32x4 br[4];
    #pragma unroll
    for (int p = 0; p < 4; ++p) {
        ar[p] = *(const f32x4*)(Xp + p * 4);
        br[p] = *(const i32x4*)(Wp + p * 4);
    }

    const int wbase = srow * 4;
    const int wswz  = (srow >> 1) & 3;
    const int ws0   = (shalf * 2)     ^ wswz;
    const int ws1   = (shalf * 2 + 1) ^ wswz;

    for (int kt = 0; kt < KDIM / 32; ++kt) {
        __syncthreads();
        {
            s16x8 v0, v1;
            #pragma unroll
            for (int q = 0; q < 8; ++q) v0[q] = f2bf(ar[q >> 2][q & 3]);
            #pragma unroll
            for (int q = 0; q < 8; ++q) v1[q] = f2bf(ar[2 + (q >> 2)][q & 3]);
            As[wbase + ws0] = v0;
            As[wbase + ws1] = v1;
            s16x8 u0, u1;
            #pragma unroll
            for (int q = 0; q < 8; ++q) u0[q] = f2bf((float)br[q >> 2][q & 3]);
            #pragma unroll
            for (int q = 0; q < 8; ++q) u1[q] = f2bf((float)br[2 + (q >> 2)][q & 3]);
            Bs[wbase + ws0] = u0;
            Bs[wbase + ws1] = u1;
        }
        __syncthreads();

        if (kt + 1 < KDIM / 32) {
            const float* Xn = Xp + (size_t)(kt + 1) * 32;
            const int*   Wn = Wp + (size_t)(kt + 1) * 32;
            #pragma unroll
            for (int p = 0; p < 4; ++p) {
                ar[p] = *(const f32x4*)(Xn + p * 4);
                br[p] = *(const i32x4*)(Wn + p * 4);
            }
        }

        s16x8 af[4], bq[4];
        #pragma unroll
        for (int i = 0; i < 4; ++i) {
            int row = wr * 64 + i * 16 + fr;
            af[i] = As[row * 4 + (fs ^ ((row >> 1) & 3))];
        }
        #pragma unroll
        for (int j = 0; j < 4; ++j) {
            int col = wc * 64 + j * 16 + fr;
            bq[j] = Bs[col * 4 + (fs ^ ((col >> 1) & 3))];
        }
        #pragma unroll
        for (int i = 0; i < 4; ++i)
            #pragma unroll
            for (int j = 0; j < 4; ++j)
                acc[i][j] = __builtin_amdgcn_mfma_f32_16x16x32_bf16(
                    af[i], bq[j], acc[i][j], 0, 0, 0);
    }

    const float scale = scale_p[0];
    #pragma unroll
    for (int j = 0; j < 4; ++j) {
        const int c  = n0 + wc * 64 + j * 16 + fr;
        const float bj = bias[c];
        #pragma unroll
        for (int i = 0; i < 4; ++i) {
            const int r0 = m0 + wr * 64 + i * 16 + fs * 4;
            float* op = Out + (size_t)r0 * NDIM + c;
            #pragma unroll
            for (int q = 0; q < 4; ++q)
                op[(size_t)q * NDIM] = acc[i][j][q] * scale + bj;
        }
    }
}

extern "C" void kernel_launch(void* const* d_in, const int* in_sizes, int n_in,
                              void* d_out, int out_size, void* d_ws, size_t ws_size,
                              hipStream_t stream) {
    const float* X     = (const float*)d_in[0];
    const int*   Wq    = (const int*)d_in[1];   // int8 widened to int32 by harness
    const float* scale = (const float*)d_in[2];
    const float* bias  = (const float*)d_in[3];
    float*       Out   = (float*)d_out;

    const size_t xBytes = (size_t)MDIM * KDIM * 2;          // 67 MB
    const size_t wBytes = (size_t)NDIM * KDIM * 2;          // 134 MB
    if (ws_size >= xBytes + wBytes) {
        ushort_t* Xbf = (ushort_t*)d_ws;
        ushort_t* Wbf = (ushort_t*)((char*)d_ws + xBytes);
        hipLaunchKernelGGL(cvt_f32_bf16, dim3(2048), dim3(256), 0, stream,
                           X, Xbf, MDIM * KDIM / 8);
        hipLaunchKernelGGL(cvt_i32_bf16, dim3(2048), dim3(256), 0, stream,
                           Wq, Wbf, NDIM * KDIM / 8);
        hipLaunchKernelGGL(sl_gemm_256m, dim3(2048), dim3(512), 0, stream,
                           Xbf, Wbf, scale, bias, Out);
    } else {
        hipLaunchKernelGGL(sl_gemm_fb, dim3(8192), dim3(256), 0, stream,
                           X, Wq, scale, bias, Out);
    }
}

// Round 9
// 1347.376 us; speedup vs baseline: 1.0970x; 1.0756x over previous
//
#include <hip/hip_runtime.h>
#include <hip/hip_bf16.h>

typedef __attribute__((ext_vector_type(4))) float f32x4;
typedef __attribute__((ext_vector_type(4))) int   i32x4;
typedef __attribute__((ext_vector_type(8))) short s16x8;
typedef unsigned short ushort_t;

#define MDIM 8192
#define KDIM 4096
#define NDIM 16384

static __device__ __forceinline__ short f2bf(float f) {
    __bf16 h = (__bf16)f;
    return __builtin_bit_cast(short, h);
}

static __device__ __forceinline__ void gload_lds16(const void* g, void* l) {
    __builtin_amdgcn_global_load_lds(
        (const __attribute__((address_space(1))) unsigned int*)g,
        (__attribute__((address_space(3))) unsigned int*)l,
        16, 0, 0);
}

// ---------------- convert kernels (memory-bound, vectorized) ----------------

__global__ __launch_bounds__(256)
void cvt_f32_bf16(const float* __restrict__ in, ushort_t* __restrict__ out, int n8) {
    for (int i = blockIdx.x * blockDim.x + threadIdx.x; i < n8;
         i += gridDim.x * blockDim.x) {
        f32x4 a = ((const f32x4*)in)[i * 2];
        f32x4 b = ((const f32x4*)in)[i * 2 + 1];
        s16x8 o;
        #pragma unroll
        for (int q = 0; q < 4; ++q) o[q] = f2bf(a[q]);
        #pragma unroll
        for (int q = 0; q < 4; ++q) o[4 + q] = f2bf(b[q]);
        ((s16x8*)out)[i] = o;
    }
}

__global__ __launch_bounds__(256)
void cvt_i32_bf16(const int* __restrict__ in, ushort_t* __restrict__ out, int n8) {
    for (int i = blockIdx.x * blockDim.x + threadIdx.x; i < n8;
         i += gridDim.x * blockDim.x) {
        i32x4 a = ((const i32x4*)in)[i * 2];
        i32x4 b = ((const i32x4*)in)[i * 2 + 1];
        s16x8 o;
        #pragma unroll
        for (int q = 0; q < 4; ++q) o[q] = f2bf((float)a[q]);   // |v|<=127: exact
        #pragma unroll
        for (int q = 0; q < 4; ++q) o[4 + q] = f2bf((float)b[q]);
        ((s16x8*)out)[i] = o;
    }
}

// ---------------- 256x256 bf16 GEMM — faithful 8-phase schedule -------------
// BK=64 K-steps; 2 LDS bufs of 64KB: {A[256][64] @0, B[256][64] @32768}.
// Rows = 128B = 8 slots of 16B; phys slot = logical ^ (row&7); swizzle applied
// on the pre-swizzled GLOBAL source (staging) and on the ds_read address.
// Iter i (8 phases) computes K-steps T=2i (buf0, ph0-3) and T+1 (buf1, ph4-7).
// Phase = quadrant (kh = phase>>1 &1, mh = phase&1): reads A(mh,kh) 4x b128
// (+ B(kh) 4x b128 on even phases), 2 gload calls (one 16KB array-half),
// barrier, lgkmcnt(0)+sched_barrier(0), setprio(1), 16 MFMA, setprio(0), barrier.
// Staging windows: T+1 -> buf1 during ph0-3 (read ph4-7, vmcnt(0)@ph3);
//                  T+2 -> buf0 during ph4-7 (read next ph0-3, vmcnt(0)@ph7).
// WAR: each region's staging starts one trailing-barrier after its last
// reader's lgkmcnt(0). RAW: vmcnt(0)+barrier precede every first read.

#define BAR()   __builtin_amdgcn_s_barrier()
#define SB0()   __builtin_amdgcn_sched_barrier(0)
#define PRIO(N) __builtin_amdgcn_s_setprio(N)
#define VM0()   asm volatile("s_waitcnt vmcnt(0)" ::: "memory")
#define LK0()   do { asm volatile("s_waitcnt lgkmcnt(0)" ::: "memory"); SB0(); } while (0)

#define RD4(D, P, IMM)                                   \
    D[0] = *(const s16x8*)((P) + (IMM));                 \
    D[1] = *(const s16x8*)((P) + (IMM) + 2048);          \
    D[2] = *(const s16x8*)((P) + (IMM) + 4096);          \
    D[3] = *(const s16x8*)((P) + (IMM) + 6144);

#define MM16(MH, AF, BF)                                                       \
    PRIO(1);                                                                   \
    _Pragma("unroll")                                                          \
    for (int mi = 0; mi < 4; ++mi)                                             \
      _Pragma("unroll")                                                        \
      for (int j = 0; j < 4; ++j)                                              \
        acc[(MH) * 4 + mi][j] = __builtin_amdgcn_mfma_f32_16x16x32_bf16(       \
            AF[mi], BF[j], acc[(MH) * 4 + mi][j], 0, 0, 0);                    \
    PRIO(0);

// stage one 16KB array-half (2 calls of 64 rows) at K-elem offset KO
#define SG2(GP, KO, LDSOFF)                                                    \
    gload_lds16((GP) + (KO), ldsc + (LDSOFF) + stw);                           \
    gload_lds16((GP) + (KO) + (size_t)64 * KDIM, ldsc + (LDSOFF) + 8192 + stw);

__global__ __launch_bounds__(512, 2)
void sl_gemm_8ph(const ushort_t* __restrict__ A, const ushort_t* __restrict__ Bw,
                 const float* __restrict__ scale_p, const float* __restrict__ bias,
                 float* __restrict__ Out)
{
    __shared__ char ldsbuf[131072];
    char* ldsc = ldsbuf;

    const int t    = threadIdx.x;
    const int lane = t & 63;
    const int wave = t >> 6;        // 0..7
    const int wr   = wave >> 2;     // 0..1 : A row-half (128 rows)
    const int wc   = wave & 3;      // 0..3 : 64 output cols

    // ---- tile mapping: XCD chunks of 256, then 16-tn panels, tm fastest
    int bid = blockIdx.x;                       // 2048 blocks (32 tm x 64 tn)
    int swz = (bid & 7) * 256 + (bid >> 3);
    int panel = swz >> 9, inp = swz & 511;
    int tn = (panel << 4) + (inp >> 5);
    int tm = inp & 31;
    const int m0 = tm << 8;
    const int n0 = tn << 8;

    // ---- staging geometry: per gload call, wave w covers 8 rows (w*8+l8);
    //      phys slot l7 holds logical slot l7^l8 (row&7 == l8)
    const int l8 = lane >> 3, l7 = lane & 7;
    const int lsl = l7 ^ l8;
    const ushort_t* gA0 = A  + (size_t)(m0 +       wave * 8 + l8) * KDIM + lsl * 8;
    const ushort_t* gA1 = A  + (size_t)(m0 + 128 + wave * 8 + l8) * KDIM + lsl * 8;
    const ushort_t* gB0 = Bw + (size_t)(n0 +       wave * 8 + l8) * KDIM + lsl * 8;
    const ushort_t* gB1 = Bw + (size_t)(n0 + 128 + wave * 8 + l8) * KDIM + lsl * 8;
    const int stw = wave * 1024;

    // ---- fragment read base pointers (per buf x kh); imm offsets cover mh/fi
    const int fr = lane & 15;
    const int fs = lane >> 4;                              // 0..3
    const int sw0 = ((fs)     ^ (fr & 7)) * 16;            // kh0 slot byte
    const int sw1 = ((fs + 4) ^ (fr & 7)) * 16;            // kh1 slot byte
    const char* pA00 = ldsc +          wr * 16384 + fr * 128 + sw0;
    const char* pA01 = ldsc +          wr * 16384 + fr * 128 + sw1;
    const char* pA10 = pA00 + 65536;
    const char* pA11 = pA01 + 65536;
    const char* pB00 = ldsc + 32768 + (wc * 64 + fr) * 128 + sw0;
    const char* pB01 = ldsc + 32768 + (wc * 64 + fr) * 128 + sw1;
    const char* pB10 = pB00 + 65536;
    const char* pB11 = pB01 + 65536;

    f32x4 acc[8][4];
    #pragma unroll
    for (int i = 0; i < 8; ++i)
        #pragma unroll
        for (int j = 0; j < 4; ++j)
            acc[i][j] = (f32x4){0.f, 0.f, 0.f, 0.f};

    s16x8 afE[4], afO[4], bf[4], bg[4];

    // ---- prologue: stage K-step 0 -> buf0, full drain, publish
    SG2(gA0, 0, 0);
    SG2(gA1, 0, 16384);
    SG2(gB0, 0, 32768);
    SG2(gB1, 0, 49152);
    VM0();
    BAR();
    SB0();

    for (int i = 0; i < 32; ++i) {
        const size_t ko1 = (size_t)(2 * i + 1) * 64;
        const size_t ko2 = (size_t)((2 * i + 2) & 63) * 64;

        // ph0: T quad(mh0,kh0); stage T+1 A-h0 -> buf1
        RD4(bf,  pB00, 0);
        RD4(afE, pA00, 0);
        SG2(gA0, ko1, 65536 + 0);
        BAR(); LK0();
        MM16(0, afE, bf);
        BAR();

        // ph1: quad(mh1,kh0); stage T+1 A-h1
        RD4(afO, pA00, 8192);
        SG2(gA1, ko1, 65536 + 16384);
        BAR(); LK0();
        MM16(1, afO, bf);
        BAR();

        // ph2: quad(mh0,kh1); stage T+1 B-h0
        RD4(bg,  pB01, 0);
        RD4(afE, pA01, 0);
        SG2(gB0, ko1, 65536 + 32768);
        BAR(); LK0();
        MM16(0, afE, bg);
        BAR();

        // ph3: quad(mh1,kh1); stage T+1 B-h1; drain T+1 before buf1 reads
        RD4(afO, pA01, 8192);
        SG2(gB1, ko1, 65536 + 49152);
        BAR(); LK0();
        MM16(1, afO, bg);
        VM0();
        BAR();

        // ph4: T+1 quad(mh0,kh0); stage T+2 A-h0 -> buf0
        RD4(bf,  pB10, 0);
        RD4(afE, pA10, 0);
        SG2(gA0, ko2, 0);
        BAR(); LK0();
        MM16(0, afE, bf);
        BAR();

        // ph5: quad(mh1,kh0); stage T+2 A-h1
        RD4(afO, pA10, 8192);
        SG2(gA1, ko2, 16384);
        BAR(); LK0();
        MM16(1, afO, bf);
        BAR();

        // ph6: quad(mh0,kh1); stage T+2 B-h0
        RD4(bg,  pB11, 0);
        RD4(afE, pA11, 0);
        SG2(gB0, ko2, 32768);
        BAR(); LK0();
        MM16(0, afE, bg);
        BAR();

        // ph7: quad(mh1,kh1); stage T+2 B-h1; drain T+2 before next-iter reads
        RD4(afO, pA11, 8192);
        SG2(gB1, ko2, 49152);
        BAR(); LK0();
        MM16(1, afO, bg);
        VM0();
        BAR();
    }

    // ---- epilogue: D col = lane&15, row = fs*4 + q; scale + bias
    const float scale = scale_p[0];
    #pragma unroll
    for (int j = 0; j < 4; ++j) {
        const int c   = n0 + wc * 64 + j * 16 + fr;
        const float bj = bias[c];
        #pragma unroll
        for (int i = 0; i < 8; ++i) {
            const int r0 = m0 + wr * 128 + i * 16 + fs * 4;
            float* op = Out + (size_t)r0 * NDIM + c;
            #pragma unroll
            for (int q = 0; q < 4; ++q)
                op[(size_t)q * NDIM] = acc[i][j][q] * scale + bj;
        }
    }
}

// ---------------- fallback (fp32 direct, no workspace) ----------------

__global__ __launch_bounds__(256, 2)
void sl_gemm_fb(const float* __restrict__ X, const int* __restrict__ Wq,
                const float* __restrict__ scale_p, const float* __restrict__ bias,
                float* __restrict__ Out)
{
    __shared__ s16x8 As[128 * 4];
    __shared__ s16x8 Bs[128 * 4];

    const int t    = threadIdx.x;
    const int lane = t & 63;
    const int wave = t >> 6;
    const int wr   = wave >> 1;
    const int wc   = wave & 1;

    int bid = blockIdx.x;
    int swz = (bid & 7) * 1024 + (bid >> 3);
    int panel   = swz >> 10;
    int inpanel = swz & 1023;
    int tn = (panel << 4) + (inpanel >> 6);
    int tm = inpanel & 63;
    const int m0 = tm << 7;
    const int n0 = tn << 7;

    const int srow  = t >> 1;
    const int shalf = t & 1;
    const float* Xp = X  + (size_t)(m0 + srow) * KDIM + shalf * 16;
    const int*   Wp = Wq + (size_t)(n0 + srow) * KDIM + shalf * 16;

    f32x4 acc[4][4];
    #pragma unroll
    for (int i = 0; i < 4; ++i)
        #pragma unroll
        for (int j = 0; j < 4; ++j)
            acc[i][j] = (f32x4){0.f, 0.f, 0.f, 0.f};

    const int fr = lane & 15;
    const int fs = lane >> 4;

    f32x4 ar[4];
    i32x4 br[4];
    #pragma unroll
    for (int p = 0; p < 4; ++p) {
        ar[p] = *(const f32x4*)(Xp + p * 4);
        br[p] = *(const i32x4*)(Wp + p * 4);
    }

    const int wbase = srow * 4;
    const int wswz  = (srow >> 1) & 3;
    const int ws0   = (shalf * 2)     ^ wswz;
    const int ws1   = (shalf * 2 + 1) ^ wswz;

    for (int kt = 0; kt < KDIM / 32; ++kt) {
        __syncthreads();
        {
            s16x8 v0, v1;
            #pragma unroll
            for (int q = 0; q < 8; ++q) v0[q] = f2bf(ar[q >> 2][q & 3]);
            #pragma unroll
            for (int q = 0; q < 8; ++q) v1[q] = f2bf(ar[2 + (q >> 2)][q & 3]);
            As[wbase + ws0] = v0;
            As[wbase + ws1] = v1;
            s16x8 u0, u1;
            #pragma unroll
            for (int q = 0; q < 8; ++q) u0[q] = f2bf((float)br[q >> 2][q & 3]);
            #pragma unroll
            for (int q = 0; q < 8; ++q) u1[q] = f2bf((float)br[2 + (q >> 2)][q & 3]);
            Bs[wbase + ws0] = u0;
            Bs[wbase + ws1] = u1;
        }
        __syncthreads();

        if (kt + 1 < KDIM / 32) {
            const float* Xn = Xp + (size_t)(kt + 1) * 32;
            const int*   Wn = Wp + (size_t)(kt + 1) * 32;
            #pragma unroll
            for (int p = 0; p < 4; ++p) {
                ar[p] = *(const f32x4*)(Xn + p * 4);
                br[p] = *(const i32x4*)(Wn + p * 4);
            }
        }

        s16x8 af[4], bq[4];
        #pragma unroll
        for (int i = 0; i < 4; ++i) {
            int row = wr * 64 + i * 16 + fr;
            af[i] = As[row * 4 + (fs ^ ((row >> 1) & 3))];
        }
        #pragma unroll
        for (int j = 0; j < 4; ++j) {
            int col = wc * 64 + j * 16 + fr;
            bq[j] = Bs[col * 4 + (fs ^ ((col >> 1) & 3))];
        }
        #pragma unroll
        for (int i = 0; i < 4; ++i)
            #pragma unroll
            for (int j = 0; j < 4; ++j)
                acc[i][j] = __builtin_amdgcn_mfma_f32_16x16x32_bf16(
                    af[i], bq[j], acc[i][j], 0, 0, 0);
    }

    const float scale = scale_p[0];
    #pragma unroll
    for (int j = 0; j < 4; ++j) {
        const int c  = n0 + wc * 64 + j * 16 + fr;
        const float bj = bias[c];
        #pragma unroll
        for (int i = 0; i < 4; ++i) {
            const int r0 = m0 + wr * 64 + i * 16 + fs * 4;
            float* op = Out + (size_t)r0 * NDIM + c;
            #pragma unroll
            for (int q = 0; q < 4; ++q)
                op[(size_t)q * NDIM] = acc[i][j][q] * scale + bj;
        }
    }
}

extern "C" void kernel_launch(void* const* d_in, const int* in_sizes, int n_in,
                              void* d_out, int out_size, void* d_ws, size_t ws_size,
                              hipStream_t stream) {
    const float* X     = (const float*)d_in[0];
    const int*   Wq    = (const int*)d_in[1];   // int8 widened to int32 by harness
    const float* scale = (const float*)d_in[2];
    const float* bias  = (const float*)d_in[3];
    float*       Out   = (float*)d_out;

    const size_t xBytes = (size_t)MDIM * KDIM * 2;          // 67 MB
    const size_t wBytes = (size_t)NDIM * KDIM * 2;          // 134 MB
    if (ws_size >= xBytes + wBytes) {
        ushort_t* Xbf = (ushort_t*)d_ws;
        ushort_t* Wbf = (ushort_t*)((char*)d_ws + xBytes);
        hipLaunchKernelGGL(cvt_f32_bf16, dim3(2048), dim3(256), 0, stream,
                           X, Xbf, MDIM * KDIM / 8);
        hipLaunchKernelGGL(cvt_i32_bf16, dim3(2048), dim3(256), 0, stream,
                           Wq, Wbf, NDIM * KDIM / 8);
        hipLaunchKernelGGL(sl_gemm_8ph, dim3(2048), dim3(512), 0, stream,
                           Xbf, Wbf, scale, bias, Out);
    } else {
        hipLaunchKernelGGL(sl_gemm_fb, dim3(8192), dim3(256), 0, stream,
                           X, Wq, scale, bias, Out);
    }
}